// Round 10
// baseline (293.722 us; speedup 1.0000x reference)
//
#include <hip/hip_runtime.h>

// ===== Problem dims =====
// B=32, L=512 -> M = 16384 rows. Inputs fp32, OUTPUTS fp32.
// GEMM1(proj): A=[emb|lang] K=640 (reg-staged fp32->f16), N=512 pad, tanh,
//   fused s1/s2. GEMM1b(aux): A=hidden K=800 pad 832 (reg-staged), tanh,
//   writes aux_cat. GEMM2(heads): A=aux_cat f16 (async16), N=820 pad 1024,
//   arcs fused.
// R10 = R6 exactly (best measured, 267us) + two critical-path micro-fixes:
//   (a) aux last K-tile (K 768-832) computes only its kk=0 half -- cols
//       800-832 are zero padding; skipping kk=1 saves 32 MFMA/wave + 12
//       ds_reads on the 13-tile aux jobs that set gemm01's makespan.
//   (b) aux_cat lang/pad cols [500,640) written by a PROJ block (10-tile
//       short job) instead of an aux block (13-tile long job).
// Free-run: ONE s_barrier per K-tile; A-pin discipline (R6).
// 3 launches: setup(weights+bias) -> gemm01 (64x4) -> gemm2+arcs (64x4).

using f16   = _Float16;
using f16x4 = __attribute__((ext_vector_type(4))) _Float16;
using f16x8 = __attribute__((ext_vector_type(8))) _Float16;  // 8 f16 (4 VGPRs)
using f32x4 = __attribute__((ext_vector_type(4))) float;     // MFMA acc

__device__ __forceinline__ f16 f2h(float f) { return (f16)f; }
__device__ __forceinline__ f16x4 cvt4(float4 v) {
  return f16x4{ f2h(v.x), f2h(v.y), f2h(v.z), f2h(v.w) };
}

// fast tanh: 1 - 2/(2^(2x*log2e)+1)
__device__ __forceinline__ float fast_tanh(float x) {
  float xc = fminf(fmaxf(x, -15.f), 15.f);
  float e  = __builtin_amdgcn_exp2f(xc * 2.885390081777927f);
  return 1.f - 2.f * __builtin_amdgcn_rcpf(e + 1.f);
}

// async global->LDS, 16B/lane; LDS dest = wave-uniform base + lane*16
__device__ __forceinline__ void async16(void* lds, const void* gp) {
  __builtin_amdgcn_global_load_lds(
      (const __attribute__((address_space(1))) unsigned int*)gp,
      (__attribute__((address_space(3))) unsigned int*)lds, 16, 0, 0);
}

// ---------------------------------------------------------------------------
// Setup (tiny): pack f16 weights + fp32 biases only.
//   W_proj[512,640] | W_auxp[512,832] | W_heads[1024,640]
// ---------------------------------------------------------------------------
__global__ __launch_bounds__(256) void setup_kernel(
    const float* __restrict__ W_arc, const float* __restrict__ b_arc,
    const float* __restrict__ W_lab, const float* __restrict__ b_lab,
    const float* __restrict__ W_aux, const float* __restrict__ b_aux,
    const float* __restrict__ W_upos, const float* __restrict__ b_upos,
    const float* __restrict__ W_xpos, const float* __restrict__ b_xpos,
    const float* __restrict__ W_attrs, const float* __restrict__ b_attrs,
    f16* __restrict__ W_proj, f16* __restrict__ W_auxp, f16* __restrict__ W_heads,
    float* __restrict__ bias_proj, float* __restrict__ bias_aux, float* __restrict__ bias_heads)
{
  const int blk = blockIdx.x, t = threadIdx.x;
  if (blk < 1376) {                          // 352,256 weight quads
    int w = blk * 256 + t;
    const float* src = nullptr;
    f16* dst;
    if (w < 81920) {                         // W_proj [512,640] : 160 q/row
      int n = w / 160, s = w - n * 160;
      dst = W_proj + (size_t)w * 4;
      if (s < 150 && n < 500)
        src = (n < 100 ? W_arc + (size_t)n * 600
                       : W_lab + (size_t)(n - 100) * 600) + s * 4;
    } else if (w < 81920 + 106496) {         // W_auxp [512,832] : 208 q/row
      int w2 = w - 81920;
      int n = w2 / 208, s = w2 - n * 208;
      dst = W_auxp + (size_t)w2 * 4;
      if (s < 200 && n < 500) src = W_aux + (size_t)n * 800 + s * 4;
    } else {                                 // W_heads [1024,640] : 160 q/row
      int w3 = w - (81920 + 106496);
      int n = w3 / 160, s = w3 - n * 160;
      dst = W_heads + (size_t)w3 * 4;
      if (s < 150 && n < 820)
        src = (n < 20 ? W_upos + (size_t)n * 600
              : n < 320 ? W_xpos + (size_t)(n - 20) * 600
                        : W_attrs + (size_t)(n - 320) * 600) + s * 4;
    }
    f16x4 h = { (f16)0.f, (f16)0.f, (f16)0.f, (f16)0.f };
    if (src) h = cvt4(*(const float4*)src);
    *(f16x4*)dst = h;
    return;
  }
  for (int idx = t; idx < 2048; idx += 256) {      // ---- biases ----
    if (idx < 512) {
      float v = 0.f;
      if (idx < 100)      v = b_arc[idx];
      else if (idx < 500) v = b_lab[idx - 100];
      bias_proj[idx] = v;
    } else if (idx < 1024) {
      int i = idx - 512;
      bias_aux[i] = (i < 500) ? b_aux[i] : 0.f;
    } else {
      int i = idx - 1024; float v = 0.f;
      if (i < 20)       v = b_upos[i];
      else if (i < 320) v = b_xpos[i - 20];
      else if (i < 820) v = b_attrs[i - 320];
      bias_heads[i] = v;
    }
  }
}

// ---------------------------------------------------------------------------
// Fused GEMM0+GEMM1 (R6 + half-tile tail), grid (64, 4), 512 threads.
//   bny<2 : proj A=[emb|lang|pad] K=640 NT=10; cols[100,500)->out_label;
//           bny==0: fused s1/s2 head dots; bny==1: aux_cat lang/pad cols
//   bny>=2: aux  A=hidden pad     K=832 NT=13 (last tile kk=0 only);
//           cols[0,500)->aux_cat
// ---------------------------------------------------------------------------
__global__ __launch_bounds__(512, 2) void gemm01(
    const float* __restrict__ emb, const float* __restrict__ hidden,
    const float* __restrict__ lang_table, const int* __restrict__ lang_ids,
    const f16* __restrict__ W_proj, const f16* __restrict__ W_auxp,
    const float* __restrict__ bias_proj, const float* __restrict__ bias_aux,
    float* __restrict__ out_label, const float* __restrict__ w_head,
    float* __restrict__ s1, float* __restrict__ s2, f16* __restrict__ aux_cat)
{
  __shared__ __align__(16) f16 ldsA[2 * 16384];
  __shared__ __align__(16) f16 ldsB[2 * 16384];
  __shared__ float s1red[2][256], s2red[2][256];

  const int tid  = threadIdx.x;
  const int lane = tid & 63;
  const int wave = tid >> 6;                 // 0..7
  const int wm = wave >> 2, wn = wave & 3;   // 2M x 4N
  const int m16 = lane & 15, quad = lane >> 4;
  const int bm  = blockIdx.x;
  const int bny = blockIdx.y;                // 0..3
  const bool is0 = (bny < 2);
  const int bn  = is0 ? bny : bny - 2;
  const int K   = is0 ? 640 : 832;
  const int NT  = is0 ? 10 : 13;

  // ---- B staging (async16, pre-swizzled source) ----
  const int sr = lane >> 3;
  const int ssB = (lane & 7) ^ sr;
  const f16* Bmat = is0 ? W_proj : W_auxp;
  const f16* gB[4];
#pragma unroll
  for (int i = 0; i < 4; ++i)
    gB[i] = Bmat + (size_t)(bn * 256 + i * 64 + wave * 8 + sr) * K + ssB * 8;
  f16* sB = ldsB + wave * 512;

  // ---- A reg-staging: lane owns 4 chunks (rows wave*32+i*8+(lane>>3),
  //      slot ssA=lane&7); lang row is block-uniform (batch = bm>>1). ----
  const int ssA = lane & 7;
  const float* lrow = lang_table + (size_t)lang_ids[bm >> 1] * 100;
  const float* srcA[4];
  int dstA[4];
#pragma unroll
  for (int i = 0; i < 4; ++i) {
    const int rowA = wave * 32 + i * 8 + (lane >> 3);
    const int grow = bm * 256 + rowA;
    srcA[i] = is0 ? emb + (size_t)grow * 500 : hidden + (size_t)grow * 800;
    dstA[i] = rowA * 64 + ((ssA ^ (rowA & 7)) * 8);
  }
  float4 va[4], vb[4];

  // ---- ds_read bases ----
  const int aBase = (wm * 128 + m16) * 64;
  const int bBase = (wn * 64  + m16) * 64;
  const int sw0 = ((quad)     ^ (m16 & 7)) * 8;
  const int sw1 = ((4 | quad) ^ (m16 & 7)) * 8;

  f32x4 acc[8][4] = {};
  f16x8 af[4], bf[4];

#define ASTAGE(tt) do { const int k0b = (tt) * 64 + ssA * 8;                    \
    _Pragma("unroll")                                                           \
    for (int i2 = 0; i2 < 4; ++i2) {                                            \
      float4 x0 = {0.f,0.f,0.f,0.f}, x1 = {0.f,0.f,0.f,0.f};                    \
      if (is0) {                                                                \
        if (k0b < 500) { x0 = *(const float4*)(srcA[i2] + k0b);                 \
          x1 = (k0b + 4 < 500) ? *(const float4*)(srcA[i2] + k0b + 4)           \
                               : *(const float4*)(lrow); }                      \
        else if (k0b < 600) { x0 = *(const float4*)(lrow + k0b - 500);          \
                              x1 = *(const float4*)(lrow + k0b - 496); }        \
      } else if (k0b < 800) { x0 = *(const float4*)(srcA[i2] + k0b);            \
                              x1 = *(const float4*)(srcA[i2] + k0b + 4); }      \
      va[i2] = x0; vb[i2] = x1; } } while (0)

#define AWRITE(nbf) do { _Pragma("unroll")                                      \
    for (int i2 = 0; i2 < 4; ++i2) {                                            \
      f16x8 hw = { f2h(va[i2].x), f2h(va[i2].y), f2h(va[i2].z), f2h(va[i2].w),  \
                   f2h(vb[i2].x), f2h(vb[i2].y), f2h(vb[i2].z), f2h(vb[i2].w) };\
      *(f16x8*)&ldsA[(nbf) + dstA[i2]] = hw; } } while (0)

#define BWISSUE(k0n, nbf) do {                                                  \
    async16(sB + (nbf) + 0 * 4096, gB[0] + (k0n));                              \
    async16(sB + (nbf) + 1 * 4096, gB[1] + (k0n));                              \
    async16(sB + (nbf) + 2 * 4096, gB[2] + (k0n));                              \
    async16(sB + (nbf) + 3 * 4096, gB[3] + (k0n)); } while (0)

#define RDA(mqv, sw) { _Pragma("unroll")                                        \
  for (int ii = 0; ii < 4; ++ii)                                                \
    af[ii] = *(const f16x8*)&ldsA[buf + aBase + (mqv) * 4096 + ii * 1024 + (sw)]; }
#define RDB(sw) { _Pragma("unroll")                                             \
  for (int j = 0; j < 4; ++j)                                                   \
    bf[j] = *(const f16x8*)&ldsB[buf + bBase + j * 1024 + (sw)]; }
#define MM(mqv) { _Pragma("unroll")                                             \
  for (int ii = 0; ii < 4; ++ii) { _Pragma("unroll")                            \
    for (int j = 0; j < 4; ++j)                                                 \
      acc[(mqv) * 4 + ii][j] = __builtin_amdgcn_mfma_f32_16x16x32_f16(          \
          af[ii], bf[j], acc[(mqv) * 4 + ii][j], 0, 0, 0); } }
#define SBAR __builtin_amdgcn_sched_barrier(0)
#define VM4  asm volatile("s_waitcnt vmcnt(4)" ::: "memory")
#define VM0  asm volatile("s_waitcnt vmcnt(0)" ::: "memory")
#define LGK0 asm volatile("s_waitcnt lgkmcnt(0)" ::: "memory")
#define BAR  __builtin_amdgcn_s_barrier()
#define PRIO1 __builtin_amdgcn_s_setprio(1)
#define PRIO0 __builtin_amdgcn_s_setprio(0)

  // ---- prologue: tile 0. A-loads first (issue-order pinned), then B
  //      async16; vmcnt(4) => all A landed, async16 still flying. ----
  ASTAGE(0);
  SBAR;
  BWISSUE(0, 0);
  SBAR; VM4; SBAR;
  AWRITE(0);
  VM0;
  LGK0;
  BAR;

  for (int t = 0; t < NT; ++t) {
    const int buf = (t & 1) << 14;           // *16384
    const int nbf = ((t + 1) & 1) << 14;
    const bool st = (t + 1 < NT);
    const int k0n = (t + 1) << 6;
    // aux last tile: K 768-832, but cols 800-832 are zero pad -> kk=0 only
    const bool half = (!is0) && (t == 12);

    // ---- free-run tile body: no intra-tile barriers ----
    RDB(sw0); RDA(0, sw0);
    if (st) ASTAGE(t + 1);
    SBAR;                      // A-loads issue before B async16
    if (st) BWISSUE(k0n, nbf);
    PRIO1; MM(0); PRIO0;
    RDA(1, sw0);
    PRIO1; MM(1); PRIO0;
    if (!half) {
      RDB(sw1); RDA(0, sw1);
      PRIO1; MM(0); PRIO0;
      RDA(1, sw1);
      PRIO1; MM(1); PRIO0;
    }
    if (st) {
      SBAR; VM4; SBAR;         // all 8 A-loads retired; 4 async16 in flight
      AWRITE(nbf);
    }
    VM0;                       // retire async16(t+1) -> publish ldsB[nbf]
    LGK0;                      // publish AWRITE ds_writes
    BAR;                       // single per-tile barrier
  }
#undef ASTAGE
#undef AWRITE
#undef BWISSUE
#undef RDA
#undef RDB
#undef MM
#undef SBAR
#undef VM4
#undef VM0
#undef LGK0
#undef BAR
#undef PRIO1
#undef PRIO0

  // ---- epilogue ----
  const int row0 = bm * 256 + wm * 128 + quad * 4;
  const int colT = bn * 256 + wn * 64 + m16;

  if (is0) {
    const float* bias = bias_proj;
    float p1[8][4] = {}, p2[8][4] = {};
    const bool haveHead = (bn == 0);
#pragma unroll
    for (int ai = 0; ai < 8; ++ai) {
#pragma unroll
      for (int j = 0; j < 4; ++j) {
        const int col = colT + j * 16;
        const float bcol = bias[col];
        float w1c = 0.f, w2c = 0.f;
        if (haveHead && col < 100) { w1c = w_head[col]; w2c = w_head[100 + col]; }
#pragma unroll
        for (int r = 0; r < 4; ++r) {
          const int row = row0 + ai * 16 + r;
          float v = fast_tanh(acc[ai][j][r] + bcol);
          if (col >= 100 && col < 500) out_label[(size_t)row * 400 + col - 100] = v;
          p1[ai][r] += v * w1c;
          p2[ai][r] += v * w2c;
        }
      }
    }
    if (haveHead) {
      if (wn < 2) {
#pragma unroll
        for (int d = 1; d < 16; d <<= 1)
#pragma unroll
          for (int ai = 0; ai < 8; ++ai)
#pragma unroll
            for (int r = 0; r < 4; ++r) {
              p1[ai][r] += __shfl_xor(p1[ai][r], d);
              p2[ai][r] += __shfl_xor(p2[ai][r], d);
            }
        if (m16 == 0) {
#pragma unroll
          for (int ai = 0; ai < 8; ++ai)
#pragma unroll
            for (int r = 0; r < 4; ++r) {
              int rl = wm * 128 + ai * 16 + quad * 4 + r;
              s1red[wn][rl] = p1[ai][r];
              s2red[wn][rl] = p2[ai][r];
            }
        }
      }
      __syncthreads();
      if (tid < 256) s1[bm * 256 + tid] = s1red[0][tid] + s1red[1][tid];
      else { int t2 = tid - 256; s2[bm * 256 + t2] = s2red[0][t2] + s2red[1][t2]; }
    } else {                                 // bny==1 (short job): aux_cat
      for (int idx = tid; idx < 256 * 35; idx += 512) {  // lang/pad [500,640)
        int rr = idx / 35, qq = idx - rr * 35;
        int col = 500 + 4 * qq;
        f16x4 h = { (f16)0.f, (f16)0.f, (f16)0.f, (f16)0.f };
        if (col < 600) h = cvt4(*(const float4*)(lrow + col - 500));
        *(f16x4*)(aux_cat + (size_t)(bm * 256 + rr) * 640 + col) = h;
      }
    }
  } else {
    const float* bias = bias_aux;
#pragma unroll
    for (int ai = 0; ai < 8; ++ai)
#pragma unroll
      for (int j = 0; j < 4; ++j) {
        const int col = colT + j * 16;
        if (col < 500) {
          const float bcol = bias[col];
#pragma unroll
          for (int r = 0; r < 4; ++r) {
            const int row = row0 + ai * 16 + r;
            aux_cat[(size_t)row * 640 + col] = f2h(fast_tanh(acc[ai][j][r] + bcol));
          }
        }
      }
  }
}

// ---------------------------------------------------------------------------
// Fused GEMM2 + arcs (R6 verbatim -- the 267us config's component),
// grid (64, 4), 512 threads, free-run 1-barrier/tile:
//   heads GEMM A=aux_cat[16384,640] B=W_heads[1024,640] K=640 NT=10;
//   cols<20 upos | <320 xpos | <820 attrs. Then arcs rows [bm*256+bn*64,+64).
// ---------------------------------------------------------------------------
__global__ __launch_bounds__(512, 2) void gemm2_arcs(
    const f16* __restrict__ aux_cat, const f16* __restrict__ W_heads,
    const float* __restrict__ bias_heads,
    const float* __restrict__ s1, const float* __restrict__ s2,
    const float* __restrict__ b_head,
    float* __restrict__ out_arcs, float* __restrict__ out_upos,
    float* __restrict__ out_xpos, float* __restrict__ out_attrs)
{
  __shared__ __align__(16) f16 ldsA[2 * 16384];
  __shared__ __align__(16) f16 ldsB[2 * 16384];

  const int tid  = threadIdx.x;
  const int lane = tid & 63;
  const int wave = tid >> 6;
  const int wm = wave >> 2, wn = wave & 3;
  const int m16 = lane & 15, quad = lane >> 4;
  const int bm = blockIdx.x, bn = blockIdx.y;
  const int K = 640, NT = 10;

  const int sr = lane >> 3;
  const int ss = (lane & 7) ^ sr;
  const f16* gA[4]; const f16* gB[4];
#pragma unroll
  for (int i = 0; i < 4; ++i) {
    gA[i] = aux_cat + (size_t)(bm * 256 + i * 64 + wave * 8 + sr) * K + ss * 8;
    gB[i] = W_heads + (size_t)(bn * 256 + i * 64 + wave * 8 + sr) * K + ss * 8;
  }
  f16* sA = ldsA + wave * 512;
  f16* sB = ldsB + wave * 512;

  const int aBase = (wm * 128 + m16) * 64;
  const int bBase = (wn * 64  + m16) * 64;
  const int sw0 = ((quad)     ^ (m16 & 7)) * 8;
  const int sw1 = ((4 | quad) ^ (m16 & 7)) * 8;

  f32x4 acc[8][4] = {};
  f16x8 af[4], bf[4];

#define STAGE8(k0n, nbf) do {                                                   \
    async16(sA + (nbf) + 0 * 4096, gA[0] + (k0n));                              \
    async16(sA + (nbf) + 1 * 4096, gA[1] + (k0n));                              \
    async16(sA + (nbf) + 2 * 4096, gA[2] + (k0n));                              \
    async16(sA + (nbf) + 3 * 4096, gA[3] + (k0n));                              \
    async16(sB + (nbf) + 0 * 4096, gB[0] + (k0n));                              \
    async16(sB + (nbf) + 1 * 4096, gB[1] + (k0n));                              \
    async16(sB + (nbf) + 2 * 4096, gB[2] + (k0n));                              \
    async16(sB + (nbf) + 3 * 4096, gB[3] + (k0n)); } while (0)

#define RDA(mqv, sw) { _Pragma("unroll")                                        \
  for (int ii = 0; ii < 4; ++ii)                                                \
    af[ii] = *(const f16x8*)&ldsA[buf + aBase + (mqv) * 4096 + ii * 1024 + (sw)]; }
#define RDB(sw) { _Pragma("unroll")                                             \
  for (int j = 0; j < 4; ++j)                                                   \
    bf[j] = *(const f16x8*)&ldsB[buf + bBase + j * 1024 + (sw)]; }
#define MM(mqv) { _Pragma("unroll")                                             \
  for (int ii = 0; ii < 4; ++ii) { _Pragma("unroll")                            \
    for (int j = 0; j < 4; ++j)                                                 \
      acc[(mqv) * 4 + ii][j] = __builtin_amdgcn_mfma_f32_16x16x32_f16(          \
          af[ii], bf[j], acc[(mqv) * 4 + ii][j], 0, 0, 0); } }
#define VM0  asm volatile("s_waitcnt vmcnt(0)" ::: "memory")
#define BAR  __builtin_amdgcn_s_barrier()
#define PRIO1 __builtin_amdgcn_s_setprio(1)
#define PRIO0 __builtin_amdgcn_s_setprio(0)

  STAGE8(0, 0);
  VM0;
  BAR;

  for (int t = 0; t < NT; ++t) {
    const int buf = (t & 1) << 14;
    const int nbf = ((t + 1) & 1) << 14;
    const bool st = (t + 1 < NT);
    const int k0n = (t + 1) << 6;

    RDB(sw0); RDA(0, sw0);
    if (st) STAGE8(k0n, nbf);
    PRIO1; MM(0); PRIO0;
    RDA(1, sw0);
    PRIO1; MM(1); PRIO0;
    RDB(sw1); RDA(0, sw1);
    PRIO1; MM(0); PRIO0;
    RDA(1, sw1);
    PRIO1; MM(1); PRIO0;
    VM0;                      // retire async16(t+1) -> publish lds[nbf]
    BAR;                      // single per-tile barrier
  }
#undef STAGE8
#undef RDA
#undef RDB
#undef MM
#undef VM0
#undef BAR
#undef PRIO1
#undef PRIO0

  const int row0 = bm * 256 + wm * 128 + quad * 4;
  const int colT = bn * 256 + wn * 64 + m16;
#pragma unroll
  for (int ai = 0; ai < 8; ++ai)
#pragma unroll
    for (int j = 0; j < 4; ++j) {
      const int col = colT + j * 16;
      const float bcol = bias_heads[col];
#pragma unroll
      for (int r = 0; r < 4; ++r) {
        const int row = row0 + ai * 16 + r;
        float v = acc[ai][j][r] + bcol;
        if (col < 20)        out_upos[(size_t)row * 20 + col] = v;
        else if (col < 320)  out_xpos[(size_t)row * 300 + col - 20] = v;
        else if (col < 820)  out_attrs[(size_t)row * 500 + col - 320] = v;
      }
    }

  // ---- arcs: 64 rows per block, 512 threads = one full row per pass ----
  const int r0 = bm * 256 + bn * 64;
  const float bh = b_head[0];
  const float s2v = s2[((r0 >> 9) << 9) + tid];
  for (int rl = 0; rl < 64; ++rl) {
    const int row = r0 + rl;
    const float s1v = s1[row] + bh;
    float* orow = out_arcs + (size_t)row * 513;
    if (tid == 0) orow[0] = 0.f;
    orow[1 + tid] = s1v + s2v;
  }
}

// ---------------------------------------------------------------------------
extern "C" void kernel_launch(void* const* d_in, const int* in_sizes, int n_in,
                              void* d_out, int out_size, void* d_ws, size_t ws_size,
                              hipStream_t stream)
{
  const float* emb      = (const float*)d_in[0];   // [32,512,500]
  const float* hidden   = (const float*)d_in[1];   // [32,512,800]
  const int*   lang_ids = (const int*)d_in[2];     // [32]
  const float* lang_tab = (const float*)d_in[3];   // [8,100]
  const float* W_arc  = (const float*)d_in[4];
  const float* b_arc  = (const float*)d_in[5];
  const float* W_lab  = (const float*)d_in[6];
  const float* b_lab  = (const float*)d_in[7];
  const float* w_head = (const float*)d_in[8];
  const float* b_head = (const float*)d_in[9];
  const float* W_aux  = (const float*)d_in[10];
  const float* b_aux  = (const float*)d_in[11];
  const float* W_upos = (const float*)d_in[12];
  const float* b_upos = (const float*)d_in[13];
  const float* W_xpos = (const float*)d_in[14];
  const float* b_xpos = (const float*)d_in[15];
  const float* W_attrs = (const float*)d_in[16];
  const float* b_attrs = (const float*)d_in[17];

  char* ws = (char*)d_ws;
  f16* aux_cat = (f16*)(ws + 0);                  // 16384*640*2 = 20,971,520
  f16* W_proj  = (f16*)(ws + 20971520);           // 512*640*2   =    655,360
  f16* W_auxp  = (f16*)(ws + 21626880);           // 512*832*2   =    851,968
  f16* W_heads = (f16*)(ws + 22478848);           // 1024*640*2  =  1,310,720
  float* bias_proj  = (float*)(ws + 23789568);    // 512*4
  float* bias_aux   = (float*)(ws + 23791616);    // 512*4
  float* bias_heads = (float*)(ws + 23793664);    // 1024*4
  float* s1         = (float*)(ws + 23797760);    // 16384*4
  float* s2         = (float*)(ws + 23863296);    // 16384*4
  // total ws use: 23,928,832 bytes

  float* out       = (float*)d_out;
  float* out_arcs  = out;                 // 8,404,992
  float* out_label = out + 8404992;       // 6,553,600
  float* out_upos  = out + 14958592;      //   327,680
  float* out_xpos  = out + 15286272;      // 4,915,200
  float* out_attrs = out + 20201472;      // 8,192,000

  setup_kernel<<<1377, 256, 0, stream>>>(
      W_arc, b_arc, W_lab, b_lab, W_aux, b_aux,
      W_upos, b_upos, W_xpos, b_xpos, W_attrs, b_attrs,
      W_proj, W_auxp, W_heads, bias_proj, bias_aux, bias_heads);

  gemm01<<<dim3(64, 4), 512, 0, stream>>>(
      emb, hidden, lang_tab, lang_ids, W_proj, W_auxp, bias_proj, bias_aux,
      out_label, w_head, s1, s2, aux_cat);

  gemm2_arcs<<<dim3(64, 4), 512, 0, stream>>>(
      aux_cat, W_heads, bias_heads, s1, s2, b_head,
      out_arcs, out_upos, out_xpos, out_attrs);
}

// Round 11
// 267.717 us; speedup vs baseline: 1.0971x; 1.0971x over previous
//
#include <hip/hip_runtime.h>

// ===== Problem dims =====
// B=32, L=512 -> M = 16384 rows. Inputs fp32, OUTPUTS fp32.
// GEMM1(proj): A=[emb|lang] K=640 (reg-staged fp32->f16), N=512 pad, tanh,
//   fused s1/s2. GEMM1b(aux): A=hidden K=800 pad 832 (reg-staged), tanh,
//   writes aux_cat (+lang/pad cols from bny==2 epilogue).
// GEMM2(heads): A=aux_cat f16 (async16), N=820 pad 1024, arcs fused.
// 256x256 tile, BK=64, 8 waves. FREE-RUN schedule: ONE s_barrier per K-tile.
// gemm01 A-landing pinned by hand (R5 post-mortem): sched_barrier after
// ASTAGE (A-loads issue before B async16), then at end-of-tile
// sched_barrier + s_waitcnt vmcnt(4) + sched_barrier + AWRITE -- vmcnt
// retires in issue order, so <=4 outstanding => all A-loads landed while
// the 4 async16 stay in flight until the explicit VM0 before the barrier.
// == R6 verbatim: the session's best measured configuration (266.8 us). ==
// 3 launches: setup(weights+bias) -> gemm01 (64x4) -> gemm2+arcs (64x4).

using f16   = _Float16;
using f16x4 = __attribute__((ext_vector_type(4))) _Float16;
using f16x8 = __attribute__((ext_vector_type(8))) _Float16;  // 8 f16 (4 VGPRs)
using f32x4 = __attribute__((ext_vector_type(4))) float;     // MFMA acc

__device__ __forceinline__ f16 f2h(float f) { return (f16)f; }
__device__ __forceinline__ f16x4 cvt4(float4 v) {
  return f16x4{ f2h(v.x), f2h(v.y), f2h(v.z), f2h(v.w) };
}

// fast tanh: 1 - 2/(2^(2x*log2e)+1)
__device__ __forceinline__ float fast_tanh(float x) {
  float xc = fminf(fmaxf(x, -15.f), 15.f);
  float e  = __builtin_amdgcn_exp2f(xc * 2.885390081777927f);
  return 1.f - 2.f * __builtin_amdgcn_rcpf(e + 1.f);
}

// async global->LDS, 16B/lane; LDS dest = wave-uniform base + lane*16
__device__ __forceinline__ void async16(void* lds, const void* gp) {
  __builtin_amdgcn_global_load_lds(
      (const __attribute__((address_space(1))) unsigned int*)gp,
      (__attribute__((address_space(3))) unsigned int*)lds, 16, 0, 0);
}

// ---------------------------------------------------------------------------
// Setup (tiny): pack f16 weights + fp32 biases only.
//   W_proj[512,640] | W_auxp[512,832] | W_heads[1024,640]
// ---------------------------------------------------------------------------
__global__ __launch_bounds__(256) void setup_kernel(
    const float* __restrict__ W_arc, const float* __restrict__ b_arc,
    const float* __restrict__ W_lab, const float* __restrict__ b_lab,
    const float* __restrict__ W_aux, const float* __restrict__ b_aux,
    const float* __restrict__ W_upos, const float* __restrict__ b_upos,
    const float* __restrict__ W_xpos, const float* __restrict__ b_xpos,
    const float* __restrict__ W_attrs, const float* __restrict__ b_attrs,
    f16* __restrict__ W_proj, f16* __restrict__ W_auxp, f16* __restrict__ W_heads,
    float* __restrict__ bias_proj, float* __restrict__ bias_aux, float* __restrict__ bias_heads)
{
  const int blk = blockIdx.x, t = threadIdx.x;
  if (blk < 1376) {                          // 352,256 weight quads
    int w = blk * 256 + t;
    const float* src = nullptr;
    f16* dst;
    if (w < 81920) {                         // W_proj [512,640] : 160 q/row
      int n = w / 160, s = w - n * 160;
      dst = W_proj + (size_t)w * 4;
      if (s < 150 && n < 500)
        src = (n < 100 ? W_arc + (size_t)n * 600
                       : W_lab + (size_t)(n - 100) * 600) + s * 4;
    } else if (w < 81920 + 106496) {         // W_auxp [512,832] : 208 q/row
      int w2 = w - 81920;
      int n = w2 / 208, s = w2 - n * 208;
      dst = W_auxp + (size_t)w2 * 4;
      if (s < 200 && n < 500) src = W_aux + (size_t)n * 800 + s * 4;
    } else {                                 // W_heads [1024,640] : 160 q/row
      int w3 = w - (81920 + 106496);
      int n = w3 / 160, s = w3 - n * 160;
      dst = W_heads + (size_t)w3 * 4;
      if (s < 150 && n < 820)
        src = (n < 20 ? W_upos + (size_t)n * 600
              : n < 320 ? W_xpos + (size_t)(n - 20) * 600
                        : W_attrs + (size_t)(n - 320) * 600) + s * 4;
    }
    f16x4 h = { (f16)0.f, (f16)0.f, (f16)0.f, (f16)0.f };
    if (src) h = cvt4(*(const float4*)src);
    *(f16x4*)dst = h;
    return;
  }
  for (int idx = t; idx < 2048; idx += 256) {      // ---- biases ----
    if (idx < 512) {
      float v = 0.f;
      if (idx < 100)      v = b_arc[idx];
      else if (idx < 500) v = b_lab[idx - 100];
      bias_proj[idx] = v;
    } else if (idx < 1024) {
      int i = idx - 512;
      bias_aux[i] = (i < 500) ? b_aux[i] : 0.f;
    } else {
      int i = idx - 1024; float v = 0.f;
      if (i < 20)       v = b_upos[i];
      else if (i < 320) v = b_xpos[i - 20];
      else if (i < 820) v = b_attrs[i - 320];
      bias_heads[i] = v;
    }
  }
}

// ---------------------------------------------------------------------------
// Fused GEMM0+GEMM1, grid (64, 4), 512 threads. A reg-staged from fp32.
//   bny<2 : proj A=[emb|lang|pad] K=640 NT=10; cols[100,500)->out_label;
//           bny==0: fused s1/s2 head dots
//   bny>=2: aux  A=hidden pad     K=832 NT=13; cols[0,500)->aux_cat;
//           bny==2 also writes aux_cat lang/pad cols [500,640)
// ---------------------------------------------------------------------------
__global__ __launch_bounds__(512, 2) void gemm01(
    const float* __restrict__ emb, const float* __restrict__ hidden,
    const float* __restrict__ lang_table, const int* __restrict__ lang_ids,
    const f16* __restrict__ W_proj, const f16* __restrict__ W_auxp,
    const float* __restrict__ bias_proj, const float* __restrict__ bias_aux,
    float* __restrict__ out_label, const float* __restrict__ w_head,
    float* __restrict__ s1, float* __restrict__ s2, f16* __restrict__ aux_cat)
{
  __shared__ __align__(16) f16 ldsA[2 * 16384];
  __shared__ __align__(16) f16 ldsB[2 * 16384];
  __shared__ float s1red[2][256], s2red[2][256];

  const int tid  = threadIdx.x;
  const int lane = tid & 63;
  const int wave = tid >> 6;                 // 0..7
  const int wm = wave >> 2, wn = wave & 3;   // 2M x 4N
  const int m16 = lane & 15, quad = lane >> 4;
  const int bm  = blockIdx.x;
  const int bny = blockIdx.y;                // 0..3
  const bool is0 = (bny < 2);
  const int bn  = is0 ? bny : bny - 2;
  const int K   = is0 ? 640 : 832;
  const int NT  = is0 ? 10 : 13;

  // ---- B staging (async16, pre-swizzled source) ----
  const int sr = lane >> 3;
  const int ssB = (lane & 7) ^ sr;
  const f16* Bmat = is0 ? W_proj : W_auxp;
  const f16* gB[4];
#pragma unroll
  for (int i = 0; i < 4; ++i)
    gB[i] = Bmat + (size_t)(bn * 256 + i * 64 + wave * 8 + sr) * K + ssB * 8;
  f16* sB = ldsB + wave * 512;

  // ---- A reg-staging: lane owns 4 chunks (rows wave*32+i*8+(lane>>3),
  //      slot ssA=lane&7); lang row is block-uniform (batch = bm>>1). ----
  const int ssA = lane & 7;
  const float* lrow = lang_table + (size_t)lang_ids[bm >> 1] * 100;
  const float* srcA[4];
  int dstA[4];
#pragma unroll
  for (int i = 0; i < 4; ++i) {
    const int rowA = wave * 32 + i * 8 + (lane >> 3);
    const int grow = bm * 256 + rowA;
    srcA[i] = is0 ? emb + (size_t)grow * 500 : hidden + (size_t)grow * 800;
    dstA[i] = rowA * 64 + ((ssA ^ (rowA & 7)) * 8);
  }
  float4 va[4], vb[4];

  // ---- ds_read bases ----
  const int aBase = (wm * 128 + m16) * 64;
  const int bBase = (wn * 64  + m16) * 64;
  const int sw0 = ((quad)     ^ (m16 & 7)) * 8;
  const int sw1 = ((4 | quad) ^ (m16 & 7)) * 8;

  f32x4 acc[8][4] = {};
  f16x8 af[4], bf[4];

#define ASTAGE(tt) do { const int k0b = (tt) * 64 + ssA * 8;                    \
    _Pragma("unroll")                                                           \
    for (int i2 = 0; i2 < 4; ++i2) {                                            \
      float4 x0 = {0.f,0.f,0.f,0.f}, x1 = {0.f,0.f,0.f,0.f};                    \
      if (is0) {                                                                \
        if (k0b < 500) { x0 = *(const float4*)(srcA[i2] + k0b);                 \
          x1 = (k0b + 4 < 500) ? *(const float4*)(srcA[i2] + k0b + 4)           \
                               : *(const float4*)(lrow); }                      \
        else if (k0b < 600) { x0 = *(const float4*)(lrow + k0b - 500);          \
                              x1 = *(const float4*)(lrow + k0b - 496); }        \
      } else if (k0b < 800) { x0 = *(const float4*)(srcA[i2] + k0b);            \
                              x1 = *(const float4*)(srcA[i2] + k0b + 4); }      \
      va[i2] = x0; vb[i2] = x1; } } while (0)

#define AWRITE(nbf) do { _Pragma("unroll")                                      \
    for (int i2 = 0; i2 < 4; ++i2) {                                            \
      f16x8 hw = { f2h(va[i2].x), f2h(va[i2].y), f2h(va[i2].z), f2h(va[i2].w),  \
                   f2h(vb[i2].x), f2h(vb[i2].y), f2h(vb[i2].z), f2h(vb[i2].w) };\
      *(f16x8*)&ldsA[(nbf) + dstA[i2]] = hw; } } while (0)

#define BWISSUE(k0n, nbf) do {                                                  \
    async16(sB + (nbf) + 0 * 4096, gB[0] + (k0n));                              \
    async16(sB + (nbf) + 1 * 4096, gB[1] + (k0n));                              \
    async16(sB + (nbf) + 2 * 4096, gB[2] + (k0n));                              \
    async16(sB + (nbf) + 3 * 4096, gB[3] + (k0n)); } while (0)

#define RDA(mqv, sw) { _Pragma("unroll")                                        \
  for (int ii = 0; ii < 4; ++ii)                                                \
    af[ii] = *(const f16x8*)&ldsA[buf + aBase + (mqv) * 4096 + ii * 1024 + (sw)]; }
#define RDB(sw) { _Pragma("unroll")                                             \
  for (int j = 0; j < 4; ++j)                                                   \
    bf[j] = *(const f16x8*)&ldsB[buf + bBase + j * 1024 + (sw)]; }
#define MM(mqv) { _Pragma("unroll")                                             \
  for (int ii = 0; ii < 4; ++ii) { _Pragma("unroll")                            \
    for (int j = 0; j < 4; ++j)                                                 \
      acc[(mqv) * 4 + ii][j] = __builtin_amdgcn_mfma_f32_16x16x32_f16(          \
          af[ii], bf[j], acc[(mqv) * 4 + ii][j], 0, 0, 0); } }
#define SBAR __builtin_amdgcn_sched_barrier(0)
#define VM4  asm volatile("s_waitcnt vmcnt(4)" ::: "memory")
#define VM0  asm volatile("s_waitcnt vmcnt(0)" ::: "memory")
#define LGK0 asm volatile("s_waitcnt lgkmcnt(0)" ::: "memory")
#define BAR  __builtin_amdgcn_s_barrier()
#define PRIO1 __builtin_amdgcn_s_setprio(1)
#define PRIO0 __builtin_amdgcn_s_setprio(0)

  // ---- prologue: tile 0. A-loads first (issue-order pinned), then B
  //      async16; vmcnt(4) => all A landed, async16 still flying. ----
  ASTAGE(0);
  SBAR;
  BWISSUE(0, 0);
  SBAR; VM4; SBAR;
  AWRITE(0);
  VM0;                       // retire async16 (publish ldsB[0])
  LGK0;                      // publish ds_writes
  BAR;

  for (int t = 0; t < NT; ++t) {
    const int buf = (t & 1) << 14;           // *16384
    const int nbf = ((t + 1) & 1) << 14;
    const bool st = (t + 1 < NT);
    const int k0n = (t + 1) << 6;

    // ---- free-run tile body: no intra-tile barriers ----
    // P0: reads of tile t + issue ALL staging for t+1 (A regs first, pinned)
    RDB(sw0); RDA(0, sw0);
    if (st) ASTAGE(t + 1);
    SBAR;                      // A-loads issue before B async16
    if (st) BWISSUE(k0n, nbf);
    PRIO1; MM(0); PRIO0;
    // P1
    RDA(1, sw0);
    PRIO1; MM(1); PRIO0;
    // P2
    RDB(sw1); RDA(0, sw1);
    PRIO1; MM(0); PRIO0;
    // P3
    RDA(1, sw1);
    PRIO1; MM(1); PRIO0;
    // land A into LDS: pinned AFTER the MFMA clusters (R5 post-mortem:
    // unpinned, the compiler sinks this wait to right after ASTAGE and
    // serializes full HBM latency into every tile)
    if (st) {
      SBAR; VM4; SBAR;         // all 8 A-loads retired; 4 async16 in flight
      AWRITE(nbf);
    }
    VM0;                       // retire async16(t+1) -> publish ldsB[nbf]
    LGK0;                      // publish AWRITE ds_writes
    BAR;                       // single per-tile barrier
  }
#undef ASTAGE
#undef AWRITE
#undef BWISSUE
#undef RDA
#undef RDB
#undef MM
#undef SBAR
#undef VM4
#undef VM0
#undef LGK0
#undef BAR
#undef PRIO1
#undef PRIO0

  // ---- epilogue ----
  const int row0 = bm * 256 + wm * 128 + quad * 4;
  const int colT = bn * 256 + wn * 64 + m16;

  if (is0) {
    const float* bias = bias_proj;
    float p1[8][4] = {}, p2[8][4] = {};
    const bool haveHead = (bn == 0);
#pragma unroll
    for (int ai = 0; ai < 8; ++ai) {
#pragma unroll
      for (int j = 0; j < 4; ++j) {
        const int col = colT + j * 16;
        const float bcol = bias[col];
        float w1c = 0.f, w2c = 0.f;
        if (haveHead && col < 100) { w1c = w_head[col]; w2c = w_head[100 + col]; }
#pragma unroll
        for (int r = 0; r < 4; ++r) {
          const int row = row0 + ai * 16 + r;
          float v = fast_tanh(acc[ai][j][r] + bcol);
          if (col >= 100 && col < 500) out_label[(size_t)row * 400 + col - 100] = v;
          p1[ai][r] += v * w1c;
          p2[ai][r] += v * w2c;
        }
      }
    }
    if (haveHead) {
      if (wn < 2) {
#pragma unroll
        for (int d = 1; d < 16; d <<= 1)
#pragma unroll
          for (int ai = 0; ai < 8; ++ai)
#pragma unroll
            for (int r = 0; r < 4; ++r) {
              p1[ai][r] += __shfl_xor(p1[ai][r], d);
              p2[ai][r] += __shfl_xor(p2[ai][r], d);
            }
        if (m16 == 0) {
#pragma unroll
          for (int ai = 0; ai < 8; ++ai)
#pragma unroll
            for (int r = 0; r < 4; ++r) {
              int rl = wm * 128 + ai * 16 + quad * 4 + r;
              s1red[wn][rl] = p1[ai][r];
              s2red[wn][rl] = p2[ai][r];
            }
        }
      }
      __syncthreads();
      if (tid < 256) s1[bm * 256 + tid] = s1red[0][tid] + s1red[1][tid];
      else { int t2 = tid - 256; s2[bm * 256 + t2] = s2red[0][t2] + s2red[1][t2]; }
    }
  } else {
    const float* bias = bias_aux;
#pragma unroll
    for (int ai = 0; ai < 8; ++ai)
#pragma unroll
      for (int j = 0; j < 4; ++j) {
        const int col = colT + j * 16;
        if (col < 500) {
          const float bcol = bias[col];
#pragma unroll
          for (int r = 0; r < 4; ++r) {
            const int row = row0 + ai * 16 + r;
            aux_cat[(size_t)row * 640 + col] = f2h(fast_tanh(acc[ai][j][r] + bcol));
          }
        }
      }
    if (bn == 0) {                           // bny==2: lang/pad cols [500,640)
      for (int idx = tid; idx < 256 * 35; idx += 512) {
        int rr = idx / 35, qq = idx - rr * 35;
        int col = 500 + 4 * qq;
        f16x4 h = { (f16)0.f, (f16)0.f, (f16)0.f, (f16)0.f };
        if (col < 600) h = cvt4(*(const float4*)(lrow + col - 500));
        *(f16x4*)(aux_cat + (size_t)(bm * 256 + rr) * 640 + col) = h;
      }
    }
  }
}

// ---------------------------------------------------------------------------
// Fused GEMM2 + arcs, grid (64, 4), 512 threads, free-run 1-barrier/tile:
//   heads GEMM A=aux_cat[16384,640] B=W_heads[1024,640] K=640 NT=10;
//   cols<20 upos | <320 xpos | <820 attrs. Then arcs rows [bm*256+bn*64,+64).
// ---------------------------------------------------------------------------
__global__ __launch_bounds__(512, 2) void gemm2_arcs(
    const f16* __restrict__ aux_cat, const f16* __restrict__ W_heads,
    const float* __restrict__ bias_heads,
    const float* __restrict__ s1, const float* __restrict__ s2,
    const float* __restrict__ b_head,
    float* __restrict__ out_arcs, float* __restrict__ out_upos,
    float* __restrict__ out_xpos, float* __restrict__ out_attrs)
{
  __shared__ __align__(16) f16 ldsA[2 * 16384];
  __shared__ __align__(16) f16 ldsB[2 * 16384];

  const int tid  = threadIdx.x;
  const int lane = tid & 63;
  const int wave = tid >> 6;
  const int wm = wave >> 2, wn = wave & 3;
  const int m16 = lane & 15, quad = lane >> 4;
  const int bm = blockIdx.x, bn = blockIdx.y;
  const int K = 640, NT = 10;

  const int sr = lane >> 3;
  const int ss = (lane & 7) ^ sr;
  const f16* gA[4]; const f16* gB[4];
#pragma unroll
  for (int i = 0; i < 4; ++i) {
    gA[i] = aux_cat + (size_t)(bm * 256 + i * 64 + wave * 8 + sr) * K + ss * 8;
    gB[i] = W_heads + (size_t)(bn * 256 + i * 64 + wave * 8 + sr) * K + ss * 8;
  }
  f16* sA = ldsA + wave * 512;
  f16* sB = ldsB + wave * 512;

  const int aBase = (wm * 128 + m16) * 64;
  const int bBase = (wn * 64  + m16) * 64;
  const int sw0 = ((quad)     ^ (m16 & 7)) * 8;
  const int sw1 = ((4 | quad) ^ (m16 & 7)) * 8;

  f32x4 acc[8][4] = {};
  f16x8 af[4], bf[4];

#define STAGE8(k0n, nbf) do {                                                   \
    async16(sA + (nbf) + 0 * 4096, gA[0] + (k0n));                              \
    async16(sA + (nbf) + 1 * 4096, gA[1] + (k0n));                              \
    async16(sA + (nbf) + 2 * 4096, gA[2] + (k0n));                              \
    async16(sA + (nbf) + 3 * 4096, gA[3] + (k0n));                              \
    async16(sB + (nbf) + 0 * 4096, gB[0] + (k0n));                              \
    async16(sB + (nbf) + 1 * 4096, gB[1] + (k0n));                              \
    async16(sB + (nbf) + 2 * 4096, gB[2] + (k0n));                              \
    async16(sB + (nbf) + 3 * 4096, gB[3] + (k0n)); } while (0)

#define RDA(mqv, sw) { _Pragma("unroll")                                        \
  for (int ii = 0; ii < 4; ++ii)                                                \
    af[ii] = *(const f16x8*)&ldsA[buf + aBase + (mqv) * 4096 + ii * 1024 + (sw)]; }
#define RDB(sw) { _Pragma("unroll")                                             \
  for (int j = 0; j < 4; ++j)                                                   \
    bf[j] = *(const f16x8*)&ldsB[buf + bBase + j * 1024 + (sw)]; }
#define MM(mqv) { _Pragma("unroll")                                             \
  for (int ii = 0; ii < 4; ++ii) { _Pragma("unroll")                            \
    for (int j = 0; j < 4; ++j)                                                 \
      acc[(mqv) * 4 + ii][j] = __builtin_amdgcn_mfma_f32_16x16x32_f16(          \
          af[ii], bf[j], acc[(mqv) * 4 + ii][j], 0, 0, 0); } }
#define VM0  asm volatile("s_waitcnt vmcnt(0)" ::: "memory")
#define BAR  __builtin_amdgcn_s_barrier()
#define PRIO1 __builtin_amdgcn_s_setprio(1)
#define PRIO0 __builtin_amdgcn_s_setprio(0)

  STAGE8(0, 0);
  VM0;
  BAR;

  for (int t = 0; t < NT; ++t) {
    const int buf = (t & 1) << 14;
    const int nbf = ((t + 1) & 1) << 14;
    const bool st = (t + 1 < NT);
    const int k0n = (t + 1) << 6;

    RDB(sw0); RDA(0, sw0);
    if (st) STAGE8(k0n, nbf);
    PRIO1; MM(0); PRIO0;
    RDA(1, sw0);
    PRIO1; MM(1); PRIO0;
    RDB(sw1); RDA(0, sw1);
    PRIO1; MM(0); PRIO0;
    RDA(1, sw1);
    PRIO1; MM(1); PRIO0;
    VM0;                      // retire async16(t+1) -> publish lds[nbf]
    BAR;                      // single per-tile barrier
  }
#undef STAGE8
#undef RDA
#undef RDB
#undef MM
#undef VM0
#undef BAR
#undef PRIO1
#undef PRIO0

  const int row0 = bm * 256 + wm * 128 + quad * 4;
  const int colT = bn * 256 + wn * 64 + m16;
#pragma unroll
  for (int ai = 0; ai < 8; ++ai)
#pragma unroll
    for (int j = 0; j < 4; ++j) {
      const int col = colT + j * 16;
      const float bcol = bias_heads[col];
#pragma unroll
      for (int r = 0; r < 4; ++r) {
        const int row = row0 + ai * 16 + r;
        float v = acc[ai][j][r] + bcol;
        if (col < 20)        out_upos[(size_t)row * 20 + col] = v;
        else if (col < 320)  out_xpos[(size_t)row * 300 + col - 20] = v;
        else if (col < 820)  out_attrs[(size_t)row * 500 + col - 320] = v;
      }
    }

  // ---- arcs: 64 rows per block, 512 threads = one full row per pass ----
  const int r0 = bm * 256 + bn * 64;
  const float bh = b_head[0];
  const float s2v = s2[((r0 >> 9) << 9) + tid];
  for (int rl = 0; rl < 64; ++rl) {
    const int row = r0 + rl;
    const float s1v = s1[row] + bh;
    float* orow = out_arcs + (size_t)row * 513;
    if (tid == 0) orow[0] = 0.f;
    orow[1 + tid] = s1v + s2v;
  }
}

// ---------------------------------------------------------------------------
extern "C" void kernel_launch(void* const* d_in, const int* in_sizes, int n_in,
                              void* d_out, int out_size, void* d_ws, size_t ws_size,
                              hipStream_t stream)
{
  const float* emb      = (const float*)d_in[0];   // [32,512,500]
  const float* hidden   = (const float*)d_in[1];   // [32,512,800]
  const int*   lang_ids = (const int*)d_in[2];     // [32]
  const float* lang_tab = (const float*)d_in[3];   // [8,100]
  const float* W_arc  = (const float*)d_in[4];
  const float* b_arc  = (const float*)d_in[5];
  const float* W_lab  = (const float*)d_in[6];
  const float* b_lab  = (const float*)d_in[7];
  const float* w_head = (const float*)d_in[8];
  const float* b_head = (const float*)d_in[9];
  const float* W_aux  = (const float*)d_in[10];
  const float* b_aux  = (const float*)d_in[11];
  const float* W_upos = (const float*)d_in[12];
  const float* b_upos = (const float*)d_in[13];
  const float* W_xpos = (const float*)d_in[14];
  const float* b_xpos = (const float*)d_in[15];
  const float* W_attrs = (const float*)d_in[16];
  const float* b_attrs = (const float*)d_in[17];

  char* ws = (char*)d_ws;
  f16* aux_cat = (f16*)(ws + 0);                  // 16384*640*2 = 20,971,520
  f16* W_proj  = (f16*)(ws + 20971520);           // 512*640*2   =    655,360
  f16* W_auxp  = (f16*)(ws + 21626880);           // 512*832*2   =    851,968
  f16* W_heads = (f16*)(ws + 22478848);           // 1024*640*2  =  1,310,720
  float* bias_proj  = (float*)(ws + 23789568);    // 512*4
  float* bias_aux   = (float*)(ws + 23791616);    // 512*4
  float* bias_heads = (float*)(ws + 23793664);    // 1024*4
  float* s1         = (float*)(ws + 23797760);    // 16384*4
  float* s2         = (float*)(ws + 23863296);    // 16384*4
  // total ws use: 23,928,832 bytes

  float* out       = (float*)d_out;
  float* out_arcs  = out;                 // 8,404,992
  float* out_label = out + 8404992;       // 6,553,600
  float* out_upos  = out + 14958592;      //   327,680
  float* out_xpos  = out + 15286272;      // 4,915,200
  float* out_attrs = out + 20201472;      // 8,192,000

  setup_kernel<<<1377, 256, 0, stream>>>(
      W_arc, b_arc, W_lab, b_lab, W_aux, b_aux,
      W_upos, b_upos, W_xpos, b_xpos, W_attrs, b_attrs,
      W_proj, W_auxp, W_heads, bias_proj, bias_aux, bias_heads);

  gemm01<<<dim3(64, 4), 512, 0, stream>>>(
      emb, hidden, lang_tab, lang_ids, W_proj, W_auxp, bias_proj, bias_aux,
      out_label, w_head, s1, s2, aux_cat);

  gemm2_arcs<<<dim3(64, 4), 512, 0, stream>>>(
      aux_cat, W_heads, bias_heads, s1, s2, b_head,
      out_arcs, out_upos, out_xpos, out_attrs);
}